// Round 3
// baseline (10.701 us; speedup 1.0000x reference)
//
#include <hip/hip_runtime.h>
#include <math.h>

// Problem constants (fixed by the reference).
constexpr int S_ = 64;
constexpr int I_ = 128;
constexpr int PAIRS = I_ * I_;                 // 16384 per s
constexpr int TILES = 8;                       // blocks per s
constexpr int PPTILE = PAIRS / TILES;          // 2048
constexpr int THREADS = 256;
constexpr int PPT = PPTILE / THREADS;          // 8 pairs per thread
constexpr int IPT = 2 * PPT;                   // 16 c2-rows per tile
constexpr int NM = 14;                         // image slots; slot 0 = (0,0,0)

typedef float v2f __attribute__((ext_vector_type(2)));

__global__ __launch_bounds__(THREADS) void diffdist_kernel(
    const float* __restrict__ f1,   // [S,I,3] fcoords1
    const float* __restrict__ f2,   // [S,I,3] fcoords2
    const float* __restrict__ M,    // [S,3,3]
    float* __restrict__ out)        // [S*I*I] dists ++ [S*I*3] cart_coords
{
    const int s    = blockIdx.x >> 3;
    const int tile = blockIdx.x & (TILES - 1);
    const int tid  = threadIdx.x;

    __shared__ float4 c1v[I_];        // cart1: x,y,z,|.|^2
    __shared__ float4 c2v[I_];        // cart2: x,y,z,|.|^2
    __shared__ float4 tc[NM];         // image m: {2tx, 2ty, 2tz, |t|^2}
    __shared__ v2f    PP[IPT][NM];    // {P(+m), P(-m)} per local c2-row

    const float* Ms = M + s * 9;
    const float m00 = Ms[0], m01 = Ms[1], m02 = Ms[2];
    const float m10 = Ms[3], m11 = Ms[4], m12 = Ms[5];
    const float m20 = Ms[6], m21 = Ms[7], m22 = Ms[8];

    // Image-vector table: 13 representatives (+their negations implied) + zero.
    // slot m -> (fa,fb,fc): fa = m>=5; fb = ((m+1)/3+1)%3-1; fc = (m+1)%3-1.
    // Computed by 14 threads once; avoids runtime-indexed register arrays.
    if (tid < NM) {
        const int m = tid;
        const float fa = (float)(m >= 5);
        const float fb = (float)(((m + 1) / 3 + 1) % 3 - 1);
        const float fc = (float)((m + 1) % 3 - 1);
        const float tx = fa * m00 + fb * m10 + fc * m20;
        const float ty = fa * m01 + fb * m11 + fc * m21;
        const float tz = fa * m02 + fb * m12 + fc * m22;
        tc[m] = make_float4(tx + tx, ty + ty, tz + tz,
                            fmaf(tx, tx, fmaf(ty, ty, tz * tz)));
    }

    // Stage cart1/cart2 rows (+ squared norms).
    {
        const int row = tid & (I_ - 1);
        const float* p = ((tid < I_) ? f1 : f2) + (size_t)(s * I_ + row) * 3;
        float a = p[0]; a -= floorf(a);
        float b = p[1]; b -= floorf(b);
        float g = p[2]; g -= floorf(g);
        const float x = fmaf(a, m00, fmaf(b, m10, g * m20));
        const float y = fmaf(a, m01, fmaf(b, m11, g * m21));
        const float z = fmaf(a, m02, fmaf(b, m12, g * m22));
        const float w = fmaf(x, x, fmaf(y, y, z * z));
        if (tid < I_) {
            c1v[row] = make_float4(x, y, z, w);
            if (tile == 0) {
                // second output: cart_coords = frac(fcoords1) @ matrix
                float* o2 = out + (size_t)S_ * PAIRS + (size_t)(s * I_ + row) * 3;
                o2[0] = x; o2[1] = y; o2[2] = z;
            }
        } else {
            c2v[row] = make_float4(x, y, z, w);
        }
    }
    __syncthreads();

    // Per-thread Q[j,m] = |c1_j|^2 -/+ c1_j . 2t_m  (28 VGPRs, j fixed).
    const int j  = tid & (I_ - 1);
    const int hi = tid >> 7;
    const float4 cj = c1v[j];
    const float hx = cj.x + cj.x, hy = cj.y + cj.y, hz = cj.z + cj.z;
    v2f Q[NM];
    #pragma unroll
    for (int m = 0; m < NM; ++m) {
        const float4 t = tc[m];
        const float wj = fmaf(cj.x, t.x, fmaf(cj.y, t.y, cj.z * t.z));
        Q[m] = (v2f){cj.w - wj, cj.w + wj};
    }

    // Cooperative P table for this tile's 16 c2-rows:
    // P(+-m) = |c2_i|^2 + |t|^2 +- c2_i . 2t_m.  Slot 0 (t=0) -> {w,w}.
    if (tid < IPT * NM) {   // 224 threads
        const int il = tid / NM;
        const int m  = tid - il * NM;
        const float4 ci = c2v[tile * IPT + il];
        const float4 t  = tc[m];
        const float vi   = fmaf(ci.x, t.x, fmaf(ci.y, t.y, ci.z * t.z));
        const float base = ci.w + t.w;
        PP[il][m] = (v2f){base + vi, base - vi};
    }
    __syncthreads();

    // Main: d^2[i,j,m] = P[i,m] + Q[j,m] - G[i,j]; G independent of m,
    // so min_m folds before subtracting G. pk_add + v_min3 per slot.
    float* od = out + (size_t)s * PAIRS + tile * PPTILE;
    #pragma unroll
    for (int p = 0; p < PPT; ++p) {
        const int il = p * 2 + hi;                    // wave-uniform
        const float4 ci = c2v[tile * IPT + il];       // broadcast b128
        const float G = fmaf(ci.x, hx, fmaf(ci.y, hy, ci.z * hz));
        v2f e = PP[il][0] + Q[0];
        float best = fminf(e.x, e.y);
        #pragma unroll
        for (int m = 1; m < NM; ++m) {
            const v2f d = PP[il][m] + Q[m];           // v_pk_add_f32
            best = fminf(best, fminf(d.x, d.y));      // v_min3_f32
        }
        od[p * THREADS + tid] = sqrtf(fmaxf(best - G, 0.0f) + 1e-10f);
    }
}

extern "C" void kernel_launch(void* const* d_in, const int* in_sizes, int n_in,
                              void* d_out, int out_size, void* d_ws, size_t ws_size,
                              hipStream_t stream) {
    const float* f1 = (const float*)d_in[0];   // fcoords1 [S,I,3]
    const float* f2 = (const float*)d_in[1];   // fcoords2 [S,I,3]
    const float* M  = (const float*)d_in[2];   // matrix   [S,3,3]
    float* out = (float*)d_out;

    dim3 grid(S_ * TILES);
    dim3 block(THREADS);
    diffdist_kernel<<<grid, block, 0, stream>>>(f1, f2, M, out);
}